// Round 8
// baseline (256.074 us; speedup 1.0000x reference)
//
#include <hip/hip_runtime.h>
#include <hip/hip_bf16.h>

// Attn: energies = out_state @ (history @ W.T).T ; softmax rows.
// S2=S1=4096, N=1024. fp32 in/out. bf16 hi/lo GEMM, 3 products
// (Ah.Bh + Al.Bh + Ah.Bl), separate hi/lo arrays (R15: -33% staged bytes).
// R17: split-K stage-1 (2 blocks/CU): total 253.7. gemm_e ~110, gemm_p ~95.
// R18 DIAGNOSIS (arith fix of R16's floor claim): gemm_e slab = 7840 cyc =
//   MFMA 3530 (768 x 4.6 cyc/CU) + LDS-read 2260 (192 KB @ 85 B/cyc) +
//   ~2000 barrier/drain -- SERIAL, because each window's forced lgkmcnt(0)
//   + sched_barrier before the MFMA cluster forbids read/MFMA overlap.
// R18: one-window-ahead register prefetch. Window w issues window w+1's
//   ds_reads BEFORE w's MFMA cluster; forced lgkm0/sched_barrier deleted;
//   compiler emits COUNTED lgkmcnt (LGKM retires in order) so w+1's reads
//   drain on the LDS pipe while w's MFMAs run. Lockstep barriers kept
//   (6/slab), setprio kept around MFMA only (R13's free-run mistakes
//   avoided). Same surgery on gemm_p (3 windows).

typedef __bf16 bf16x8 __attribute__((ext_vector_type(8)));
typedef float f32x4 __attribute__((ext_vector_type(4)));
typedef unsigned short u16x4 __attribute__((ext_vector_type(4)));

__device__ __forceinline__ unsigned short f2bf(float x) {
  unsigned int u = __float_as_uint(x);
  u += 0x7fffu + ((u >> 16) & 1u);   // RNE
  return (unsigned short)(u >> 16);
}
__device__ __forceinline__ float bf2f(unsigned short h) {
  return __uint_as_float(((unsigned int)h) << 16);
}

__device__ __forceinline__ void async_copy_16(void* lds, const void* gsrc) {
  __builtin_amdgcn_global_load_lds(
      (const __attribute__((address_space(1))) void*)gsrc,
      (__attribute__((address_space(3))) void*)lds, 16, 0, 0);
}

__device__ __forceinline__ void barrier_fenced() {
  asm volatile("" ::: "memory");
  __builtin_amdgcn_s_barrier();
  asm volatile("" ::: "memory");
}

// Split fp32 X[rows x 1024] -> Yh, Yl [rows x 1024] bf16 (hi + residual-lo).
__global__ __launch_bounds__(256)
void split_kernel(const float* __restrict__ X, unsigned short* __restrict__ Yh,
                  unsigned short* __restrict__ Yl) {
  const size_t row = blockIdx.x;
  const int c4 = threadIdx.x;
  float4 x = ((const float4*)(X + row * 1024))[c4];
  float xs[4] = {x.x, x.y, x.z, x.w};
  u16x4 h, l;
#pragma unroll
  for (int i = 0; i < 4; ++i) {
    unsigned short hh = f2bf(xs[i]);
    h[i] = hh;
    l[i] = f2bf(xs[i] - bf2f(hh));
  }
  ((u16x4*)(Yh + row * 1024))[c4] = h;
  ((u16x4*)(Yl + row * 1024))[c4] = l;
}

// ============================ stage-2: energies =============================
// C[4096,4096] = Ah.Bh^T + Al.Bh^T + Ah.Bl^T, K=1024. 256x256 tile, 8 waves
// (2x4), wave tile 128x64. NBUF=2. Pipelined windows: reads one window
// ahead, compiler-counted lgkm overlap, barriers 6/slab, boundary drain.
// Fragment-ordered LDS: 16-row group g at byte g*1024 + lane*16; matches
// global_load_lds wave-uniform-base + lane*16; 2-way bank alias only.
__global__ __launch_bounds__(512, 2)
void gemm_e(const unsigned short* __restrict__ Ah, const unsigned short* __restrict__ Al,
            const unsigned short* __restrict__ Bh, const unsigned short* __restrict__ Bl,
            float* __restrict__ C) {
  constexpr int MT = 8, NT = 4, NA = 2, NB = 2, NTILES = 32;
  __shared__ unsigned short AhS[2][256 * 32];
  __shared__ unsigned short AlS[2][256 * 32];
  __shared__ unsigned short BhS[2][256 * 32];
  __shared__ unsigned short BlS[2][256 * 32];

  const int tid = threadIdx.x;
  const int w = tid >> 6;
  const int lane = tid & 63;
  const int wm = w >> 2, wn = w & 3;
  const int lr = lane & 15;
  const int ls = lane >> 4;

  // XCD swizzle: grid 256 = 8 XCDs x 32; bijective
  const int id = blockIdx.x;
  const int xcd = id & 7;
  const int j = id >> 3;
  const int bm = ((xcd % 4) * 4 + (j % 4)) * 256;
  const int bn = ((xcd / 4) * 8 + (j / 4)) * 256;

  const unsigned short *pah[NA], *pal[NA];
#pragma unroll
  for (int c = 0; c < NA; ++c) {
    const size_t r = (size_t)(bm + (w * NA + c) * 16 + lr) * 1024 + ls * 8;
    pah[c] = Ah + r; pal[c] = Al + r;
  }
  const unsigned short *pbh[NB], *pbl[NB];
#pragma unroll
  for (int c = 0; c < NB; ++c) {
    const size_t r = (size_t)(bn + (w * NB + c) * 16 + lr) * 1024 + ls * 8;
    pbh[c] = Bh + r; pbl[c] = Bl + r;
  }

  f32x4 acc[MT][NT] = {};

  auto stageAh = [&](int buf, int t) {
#pragma unroll
    for (int c = 0; c < NA; ++c)
      async_copy_16(&AhS[buf][(w * NA + c) * 512], pah[c] + t * 32);
  };
  auto stageAl = [&](int buf, int t) {
#pragma unroll
    for (int c = 0; c < NA; ++c)
      async_copy_16(&AlS[buf][(w * NA + c) * 512], pal[c] + t * 32);
  };
  auto stageBh = [&](int buf, int t) {
#pragma unroll
    for (int c = 0; c < NB; ++c)
      async_copy_16(&BhS[buf][(w * NB + c) * 512], pbh[c] + t * 32);
  };
  auto stageBl = [&](int buf, int t) {
#pragma unroll
    for (int c = 0; c < NB; ++c)
      async_copy_16(&BlS[buf][(w * NB + c) * 512], pbl[c] + t * 32);
  };
  auto LDAh = [&](int buf, int g) { return *(const bf16x8*)&AhS[buf][g * 512 + ls * 128 + lr * 8]; };
  auto LDAl = [&](int buf, int g) { return *(const bf16x8*)&AlS[buf][g * 512 + ls * 128 + lr * 8]; };
  auto LDBh = [&](int buf, int g) { return *(const bf16x8*)&BhS[buf][g * 512 + ls * 128 + lr * 8]; };
  auto LDBl = [&](int buf, int g) { return *(const bf16x8*)&BlS[buf][g * 512 + ls * 128 + lr * 8]; };

  stageAh(0, 0); stageAl(0, 0); stageBh(0, 0); stageBl(0, 0);
  asm volatile("s_waitcnt vmcnt(0)" ::: "memory");
  barrier_fenced();

#pragma unroll 1
  for (int t = 0; t < NTILES; ++t) {
    const int buf = t & 1, nb = buf ^ 1;
    const bool st = (t + 1 < NTILES);
    bf16x8 ah[8], al[8], bh[4], bl[4];

    // w0 (refill): read ah[0..4)+bh; issue Ah(t+1)
#pragma unroll
    for (int mt = 0; mt < 4; ++mt) ah[mt] = LDAh(buf, wm * MT + mt);
#pragma unroll
    for (int nt = 0; nt < 4; ++nt) bh[nt] = LDBh(buf, wn * NT + nt);
    if (st) stageAh(nb, t + 1);
    barrier_fenced();

    // w1: read ah[4..8) (for w2); issue Bh(t+1); MFMA ah[0..4) x bh
    //     (compiler inserts lgkmcnt(4): ah[4..8) reads drain under MFMA)
#pragma unroll
    for (int mt = 4; mt < 8; ++mt) ah[mt] = LDAh(buf, wm * MT + mt);
    if (st) stageBh(nb, t + 1);
    __builtin_amdgcn_s_setprio(1);
#pragma unroll
    for (int mt = 0; mt < 4; ++mt)
#pragma unroll
      for (int nt = 0; nt < 4; ++nt)
        acc[mt][nt] = __builtin_amdgcn_mfma_f32_16x16x32_bf16(ah[mt], bh[nt], acc[mt][nt], 0, 0, 0);
    __builtin_amdgcn_s_setprio(0);
    barrier_fenced();

    // w2: read bl (for w3); issue Al(t+1); MFMA ah[4..8) x bh
#pragma unroll
    for (int nt = 0; nt < 4; ++nt) bl[nt] = LDBl(buf, wn * NT + nt);
    if (st) stageAl(nb, t + 1);
    __builtin_amdgcn_s_setprio(1);
#pragma unroll
    for (int mt = 4; mt < 8; ++mt)
#pragma unroll
      for (int nt = 0; nt < 4; ++nt)
        acc[mt][nt] = __builtin_amdgcn_mfma_f32_16x16x32_bf16(ah[mt], bh[nt], acc[mt][nt], 0, 0, 0);
    __builtin_amdgcn_s_setprio(0);
    barrier_fenced();

    // w3: read al[0..4) (for w5); issue Bl(t+1); MFMA ah[0..4) x bl
#pragma unroll
    for (int mt = 0; mt < 4; ++mt) al[mt] = LDAl(buf, wm * MT + mt);
    if (st) stageBl(nb, t + 1);
    __builtin_amdgcn_s_setprio(1);
#pragma unroll
    for (int mt = 0; mt < 4; ++mt)
#pragma unroll
      for (int nt = 0; nt < 4; ++nt)
        acc[mt][nt] = __builtin_amdgcn_mfma_f32_16x16x32_bf16(ah[mt], bl[nt], acc[mt][nt], 0, 0, 0);
    __builtin_amdgcn_s_setprio(0);
    barrier_fenced();

    // w4: read al[4..8); MFMA ah[4..8) x bl
#pragma unroll
    for (int mt = 4; mt < 8; ++mt) al[mt] = LDAl(buf, wm * MT + mt);
    __builtin_amdgcn_s_setprio(1);
#pragma unroll
    for (int mt = 4; mt < 8; ++mt)
#pragma unroll
      for (int nt = 0; nt < 4; ++nt)
        acc[mt][nt] = __builtin_amdgcn_mfma_f32_16x16x32_bf16(ah[mt], bl[nt], acc[mt][nt], 0, 0, 0);
    __builtin_amdgcn_s_setprio(0);
    barrier_fenced();

    // w5: MFMA al x bh (32)
    __builtin_amdgcn_s_setprio(1);
#pragma unroll
    for (int mt = 0; mt < 8; ++mt)
#pragma unroll
      for (int nt = 0; nt < 4; ++nt)
        acc[mt][nt] = __builtin_amdgcn_mfma_f32_16x16x32_bf16(al[mt], bh[nt], acc[mt][nt], 0, 0, 0);
    __builtin_amdgcn_s_setprio(0);

    // boundary: drain slab t+1's DMAs + our reads of buf (recycled next)
    __builtin_amdgcn_sched_barrier(0);
    asm volatile("s_waitcnt vmcnt(0) lgkmcnt(0)" ::: "memory");
    barrier_fenced();
  }

  // Epilogue. C/D layout: col = lane&15, row = (lane>>4)*4 + reg.
  const int cm0 = bm + wm * 128;
  const int cn0 = bn + wn * 64;
#pragma unroll
  for (int mt = 0; mt < MT; ++mt)
#pragma unroll
    for (int nt = 0; nt < NT; ++nt) {
      const int col = cn0 + nt * 16 + lr;
      const int row0 = cm0 + mt * 16 + ls * 4;
#pragma unroll
      for (int r = 0; r < 4; ++r)
        C[(size_t)(row0 + r) * 4096 + col] = acc[mt][nt][r];
    }
}

// ============================ stage-1: proj (split-K) =======================
// Cpart[kh][4096,1024] = partial over K-half kh. 128x128 tile, 8 waves,
// wave tile 64x32. NBUF=2 -> 64 KB -> 2 blocks/CU. Pipelined 3 windows.
__global__ __launch_bounds__(512, 2)
void gemm_p(const unsigned short* __restrict__ Ah, const unsigned short* __restrict__ Al,
            const unsigned short* __restrict__ Bh, const unsigned short* __restrict__ Bl,
            float* __restrict__ Cpart) {
  constexpr int MT = 4, NT = 2, NTILES = 16;
  __shared__ unsigned short AhS[2][128 * 32];
  __shared__ unsigned short AlS[2][128 * 32];
  __shared__ unsigned short BhS[2][128 * 32];
  __shared__ unsigned short BlS[2][128 * 32];

  const int tid = threadIdx.x;
  const int w = tid >> 6;
  const int lane = tid & 63;
  const int wm = w >> 2, wn = w & 3;
  const int lr = lane & 15;
  const int ls = lane >> 4;

  // grid 512 = 2 K-halves x 256 tiles; XCD-swizzled tile part
  const int kh = blockIdx.x >> 8;
  const int rid = blockIdx.x & 255;
  const int xcd = rid & 7;
  const int j = rid >> 3;
  const int bm = ((xcd % 4) * 8 + (j % 8)) * 128;
  const int bn = ((xcd / 4) * 4 + (j / 8)) * 128;
  const int koff = kh * 512;
  float* __restrict__ C = Cpart + (size_t)kh * 4096 * 1024;

  const unsigned short *pah, *pal, *pbh, *pbl;
  {
    const size_t ra = (size_t)(bm + w * 16 + lr) * 1024 + koff + ls * 8;
    pah = Ah + ra; pal = Al + ra;
    const size_t rb = (size_t)(bn + w * 16 + lr) * 1024 + koff + ls * 8;
    pbh = Bh + rb; pbl = Bl + rb;
  }

  f32x4 acc[MT][NT] = {};

  auto stage_all = [&](int buf, int t) {
    async_copy_16(&AhS[buf][w * 512], pah + t * 32);
    async_copy_16(&BhS[buf][w * 512], pbh + t * 32);
    async_copy_16(&BlS[buf][w * 512], pbl + t * 32);
    async_copy_16(&AlS[buf][w * 512], pal + t * 32);
  };
  auto LDAh = [&](int buf, int g) { return *(const bf16x8*)&AhS[buf][g * 512 + ls * 128 + lr * 8]; };
  auto LDAl = [&](int buf, int g) { return *(const bf16x8*)&AlS[buf][g * 512 + ls * 128 + lr * 8]; };
  auto LDBh = [&](int buf, int g) { return *(const bf16x8*)&BhS[buf][g * 512 + ls * 128 + lr * 8]; };
  auto LDBl = [&](int buf, int g) { return *(const bf16x8*)&BlS[buf][g * 512 + ls * 128 + lr * 8]; };

  stage_all(0, 0);
  asm volatile("s_waitcnt vmcnt(0)" ::: "memory");
  barrier_fenced();

#pragma unroll 1
  for (int t = 0; t < NTILES; ++t) {
    const int buf = t & 1, nb = buf ^ 1;
    const bool st = (t + 1 < NTILES);
    bf16x8 ah[4], al[4], bh[2], bl[2];

    // w0 (refill): read ah,bh,bl; issue slab t+1
#pragma unroll
    for (int mt = 0; mt < 4; ++mt) ah[mt] = LDAh(buf, wm * MT + mt);
#pragma unroll
    for (int nt = 0; nt < 2; ++nt) bh[nt] = LDBh(buf, wn * NT + nt);
#pragma unroll
    for (int nt = 0; nt < 2; ++nt) bl[nt] = LDBl(buf, wn * NT + nt);
    if (st) stage_all(nb, t + 1);
    barrier_fenced();

    // w1: read al (for w2); MFMA ah.bh + ah.bl (16)
    //     (compiler-counted lgkm: al reads drain under the MFMAs)
#pragma unroll
    for (int mt = 0; mt < 4; ++mt) al[mt] = LDAl(buf, wm * MT + mt);
    __builtin_amdgcn_s_setprio(1);
#pragma unroll
    for (int mt = 0; mt < 4; ++mt)
#pragma unroll
      for (int nt = 0; nt < 2; ++nt)
        acc[mt][nt] = __builtin_amdgcn_mfma_f32_16x16x32_bf16(ah[mt], bh[nt], acc[mt][nt], 0, 0, 0);
#pragma unroll
    for (int mt = 0; mt < 4; ++mt)
#pragma unroll
      for (int nt = 0; nt < 2; ++nt)
        acc[mt][nt] = __builtin_amdgcn_mfma_f32_16x16x32_bf16(ah[mt], bl[nt], acc[mt][nt], 0, 0, 0);
    __builtin_amdgcn_s_setprio(0);
    barrier_fenced();

    // w2: MFMA al.bh (8)
    __builtin_amdgcn_s_setprio(1);
#pragma unroll
    for (int mt = 0; mt < 4; ++mt)
#pragma unroll
      for (int nt = 0; nt < 2; ++nt)
        acc[mt][nt] = __builtin_amdgcn_mfma_f32_16x16x32_bf16(al[mt], bh[nt], acc[mt][nt], 0, 0, 0);
    __builtin_amdgcn_s_setprio(0);

    // boundary
    __builtin_amdgcn_sched_barrier(0);
    asm volatile("s_waitcnt vmcnt(0) lgkmcnt(0)" ::: "memory");
    barrier_fenced();
  }

  // Epilogue: fp32 partial write.
  const int cm0 = bm + wm * 64;
  const int cn0 = bn + wn * 32;
#pragma unroll
  for (int mt = 0; mt < MT; ++mt)
#pragma unroll
    for (int nt = 0; nt < NT; ++nt) {
      const int col = cn0 + nt * 16 + lr;
      const int row0 = cm0 + mt * 16 + ls * 4;
#pragma unroll
      for (int r = 0; r < 4; ++r)
        C[(size_t)(row0 + r) * 1024 + col] = acc[mt][nt][r];
    }
}

// P = Pa + Pb; split hi/lo into Ph, Pl. Row per block.
__global__ __launch_bounds__(256)
void reduce_split(const float* __restrict__ Pa, const float* __restrict__ Pb,
                  unsigned short* __restrict__ Ph, unsigned short* __restrict__ Pl) {
  const size_t row = blockIdx.x;
  const int c4 = threadIdx.x;
  float4 a = ((const float4*)(Pa + row * 1024))[c4];
  float4 b = ((const float4*)(Pb + row * 1024))[c4];
  float s[4] = {a.x + b.x, a.y + b.y, a.z + b.z, a.w + b.w};
  u16x4 h, l;
#pragma unroll
  for (int i = 0; i < 4; ++i) {
    unsigned short hh = f2bf(s[i]);
    h[i] = hh;
    l[i] = f2bf(s[i] - bf2f(hh));
  }
  ((u16x4*)(Ph + row * 1024))[c4] = h;
  ((u16x4*)(Pl + row * 1024))[c4] = l;
}

// In-place row softmax, N=4096, one block per row, 16 floats/thread in regs.
__global__ __launch_bounds__(256)
void softmax_inplace(float* __restrict__ C, int N) {
  float4* r4 = (float4*)(C + (size_t)blockIdx.x * N);
  const int t = threadIdx.x;
  float4 v[4];
  float mx = -3.0e38f;
#pragma unroll
  for (int i = 0; i < 4; ++i) {
    v[i] = r4[t + i * 256];
    mx = fmaxf(mx, fmaxf(fmaxf(v[i].x, v[i].y), fmaxf(v[i].z, v[i].w)));
  }
#pragma unroll
  for (int o = 32; o; o >>= 1) mx = fmaxf(mx, __shfl_xor(mx, o, 64));
  __shared__ float smax[4], ssum[4];
  const int w = t >> 6;
  if ((t & 63) == 0) smax[w] = mx;
  __syncthreads();
  mx = fmaxf(fmaxf(smax[0], smax[1]), fmaxf(smax[2], smax[3]));
  float s = 0.f;
#pragma unroll
  for (int i = 0; i < 4; ++i) {
    v[i].x = __expf(v[i].x - mx);
    v[i].y = __expf(v[i].y - mx);
    v[i].z = __expf(v[i].z - mx);
    v[i].w = __expf(v[i].w - mx);
    s += (v[i].x + v[i].y) + (v[i].z + v[i].w);
  }
#pragma unroll
  for (int o = 32; o; o >>= 1) s += __shfl_xor(s, o, 64);
  if ((t & 63) == 0) ssum[w] = s;
  __syncthreads();
  const float inv = 1.0f / (ssum[0] + ssum[1] + ssum[2] + ssum[3]);
#pragma unroll
  for (int i = 0; i < 4; ++i) {
    v[i].x *= inv; v[i].y *= inv; v[i].z *= inv; v[i].w *= inv;
    r4[t + i * 256] = v[i];
  }
}

extern "C" void kernel_launch(void* const* d_in, const int* in_sizes, int n_in,
                              void* d_out, int out_size, void* d_ws, size_t ws_size,
                              hipStream_t stream) {
  const float* out_state = (const float*)d_in[0];  // [4096,1024]
  const float* history   = (const float*)d_in[1];  // [4096,1024]
  const float* W         = (const float*)d_in[2];  // [1024,1024]
  float* out = (float*)d_out;                      // [4096,4096]

  unsigned short* Hh = (unsigned short*)d_ws;                 // 4096x1024 each
  unsigned short* Hl = Hh + (size_t)4096 * 1024;
  unsigned short* Wh = Hl + (size_t)4096 * 1024;              // 1024x1024
  unsigned short* Wl = Wh + (size_t)1024 * 1024;
  unsigned short* Ah = Wl + (size_t)1024 * 1024;              // 4096x1024
  unsigned short* Al = Ah + (size_t)4096 * 1024;
  unsigned short* Ph = Al + (size_t)4096 * 1024;              // 4096x1024
  unsigned short* Pl = Ph + (size_t)4096 * 1024;
  float* P32 = (float*)(Pl + (size_t)4096 * 1024);            // 2 x 4096x1024 fp32

  split_kernel<<<4096, 256, 0, stream>>>(history, Hh, Hl);
  split_kernel<<<1024, 256, 0, stream>>>(W, Wh, Wl);
  split_kernel<<<4096, 256, 0, stream>>>(out_state, Ah, Al);

  // stage-1: split-K proj. 512 blocks (2 K-halves), 2 blocks/CU, pipelined.
  gemm_p<<<512, 512, 0, stream>>>(Hh, Hl, Wh, Wl, P32);
  reduce_split<<<4096, 256, 0, stream>>>(P32, P32 + (size_t)4096 * 1024, Ph, Pl);

  // stage-2: energies. Pipelined 6-window slab, 256 blocks.
  gemm_e<<<256, 512, 0, stream>>>(Ah, Al, Ph, Pl, out);

  softmax_inplace<<<4096, 256, 0, stream>>>(out, 4096);
}